// Round 9
// baseline (197.345 us; speedup 1.0000x reference)
//
#include <hip/hip_runtime.h>
#include <hip/hip_bf16.h>
#include <stdint.h>

// VectorQuantizer on MI355X (gfx950) — round 14
// inputs: x [64,256,32,32] fp32 (NCHW), codebook [1024,256] fp32
// outputs: q_st [64,256,32,32] fp32, loss scalar
//
// R14 = R6/R11 (77 us vq_main, the proven best) with LDS shrunk 34304 -> 32768
// so a 4th block/CU fits (R11 showed (256,4) bounds alone couldn't get there:
// 34.3KB x 4 = 137KB missed the schedulable-LDS quantum; 32KB x 4 = 128KB).
// Changes are strictly OUTSIDE the hot loop: smin/sidx/sfin overlay the dead
// xt buffer post-K-loop (one extra barrier), sxsq replaced by per-wave atomic
// ||x||^2 partials. Staging, K-loop, scan, epilogue byte-identical to R11 —
// R7-R10 proved the 77 us codegen is a fragile local optimum; this perturbs
// only occupancy. R12/R13's 2-blocks/CU pipelines (90-94 us) lost to R6's
// 3-blocks/CU TLP; this bets further on the same mechanism: 12 -> 16 waves/CU.

#define DIM 256

typedef __attribute__((ext_vector_type(8)))  short bf16x8_t;   // MFMA A/B frag (4 VGPRs)
typedef __attribute__((ext_vector_type(4)))  float f32x4_t;
typedef __attribute__((ext_vector_type(16))) float f32x16_t;   // 32x32 C/D frag

__device__ __forceinline__ uint32_t f2bf(float f) {
    union { float f; uint32_t u; } v; v.f = f;
    uint32_t r = v.u + 0x7FFFu + ((v.u >> 16) & 1u);   // RNE
    return r >> 16;
}

// ---- prep: one wave per code. Emits (a) bf16 codebook in exact MFMA A-frag
// order: entry e=(mt*16+ks)*64+lane2 holds cb[mt*32+(lane2&31)][ks*16+(lane2>>5)*8+j],
// and (b) -0.5*||c||^2 in C/D-register order (nh_ord[mt*32 + half*16 + r]).
__global__ __launch_bounds__(256) void vq_prep(const float* __restrict__ cb,
                                               char* __restrict__ cbsw,
                                               float* __restrict__ nh_ord) {
    const int code = blockIdx.x * 4 + (threadIdx.x >> 6);
    const int l    = threadIdx.x & 63;               // holds d = 4l..4l+3
    const f32x4_t v = ((const f32x4_t*)(cb + code * DIM))[l];
    float sq = v.x * v.x + v.y * v.y + v.z * v.z + v.w * v.w;

    const int mt = code >> 5;
    const int ks = l >> 2;               // d/16
    const int hl = (l >> 1) & 1;         // (d%16)/8
    const uint32_t ebyte = (uint32_t)(((mt * 16 + ks) * 64 + (code & 31) + 32 * hl) * 16
                                      + (l & 1) * 8);
    uint2 o;
    o.x = f2bf(v.x) | (f2bf(v.y) << 16);
    o.y = f2bf(v.z) | (f2bf(v.w) << 16);
    *(uint2*)(cbsw + ebyte) = o;

    #pragma unroll
    for (int m = 32; m; m >>= 1) sq += __shfl_xor(sq, m);
    if (l == 0) {
        const int rw = code & 31;
        const int h4 = (rw >> 2) & 1;
        const int r  = (rw & 3) | ((rw >> 3) << 2);
        nh_ord[mt * 32 + h4 * 16 + r] = -0.5f * sq;
    }
}

// ---- main: 1024 blocks x 256 threads; block = 64 hw rows.
// LDS xt entry E=(ks*2+half)*64+row holds x[row][ks*16+half*8 .. +7] as 8 bf16 (16 B).
// Wave w: n-tile nt=w&1 (rows nt*32..), code-half ch=w>>1 (codes ch*512..).
// LDS = exactly 32 KB; result arrays overlay xt after the K-loop (xt dead).
__global__ __launch_bounds__(256, 4) void vq_main(const float* __restrict__ x,
                                                  const float* __restrict__ cb,
                                                  const bf16x8_t* __restrict__ cbsw,
                                                  const float* __restrict__ nh_ord,
                                                  float* __restrict__ out,
                                                  float* __restrict__ loss_accum) {
    __shared__ uint32_t xt[16 * 2 * 64 * 4];   // 32768 B exactly, B-frag order

    const int t     = threadIdx.x;
    const int w     = t >> 6;
    const int lane  = t & 63;
    const int n0    = blockIdx.x * 64;
    const int batch = n0 >> 10;
    const int hw0   = n0 & 1023;

    // ---- stage x -> LDS in fragment order (conflict-free b128 writes) + ||x||^2
    float sqw;   // wave's ||x||^2 partial (all 64 lanes hold the wave sum)
    {
        const int col = t & 63;          // hw row within block
        const int oct = t >> 6;          // 0..3: d-octet selector
        const float* xp = x + (size_t)batch * (DIM * 1024) + hw0 + col;
        float sq = 0.f;
        #pragma unroll
        for (int i = 0; i < 8; ++i) {
            const int d0 = oct * 8 + i * 32;     // 8 consecutive d, one LDS entry
            float a[8];
            #pragma unroll
            for (int j = 0; j < 8; ++j) {
                a[j] = xp[(size_t)(d0 + j) * 1024];
                sq += a[j] * a[j];
            }
            uint4 pk;
            pk.x = f2bf(a[0]) | (f2bf(a[1]) << 16);
            pk.y = f2bf(a[2]) | (f2bf(a[3]) << 16);
            pk.z = f2bf(a[4]) | (f2bf(a[5]) << 16);
            pk.w = f2bf(a[6]) | (f2bf(a[7]) << 16);
            const int ks   = d0 >> 4;
            const int half = (d0 >> 3) & 1;
            *(uint4*)&xt[(ks * 512) + (half * 256) + col * 4] = pk;
        }
        #pragma unroll
        for (int m = 32; m; m >>= 1) sq += __shfl_xor(sq, m);
        sqw = sq;
    }
    __syncthreads();

    // ---- K-loop: wave's 512 codes (16 m-tiles); argmax(dot - 0.5*||c||^2)
    const int nt   = w & 1;
    const int ch   = w >> 1;
    const int half = lane >> 5;
    const int col  = lane & 31;
    const uint32_t* xbase = xt + half * 256 + (nt * 32 + col) * 4;

    float best = -3.0e38f;
    int   bi = 0;
    for (int i = 0; i < 16; ++i) {
        const int mt = ch * 16 + i;

        // batch-prefetch all 16 A-frags of this m-tile (16 independent
        // global_load_dwordx4 issued before any MFMA consumes them)
        bf16x8_t apre[16];
        {
            const bf16x8_t* ap = cbsw + mt * (16 * 64) + lane;
            #pragma unroll
            for (int ks = 0; ks < 16; ++ks) apre[ks] = ap[ks * 64];
        }

        const f32x4_t* nhp = (const f32x4_t*)(nh_ord + mt * 32 + half * 16);
        const f32x4_t h0 = nhp[0], h1 = nhp[1], h2 = nhp[2], h3 = nhp[3];
        f32x16_t acc;
        #pragma unroll
        for (int r = 0; r < 4; ++r) {
            acc[r] = h0[r]; acc[4 + r] = h1[r]; acc[8 + r] = h2[r]; acc[12 + r] = h3[r];
        }
        #pragma unroll
        for (int ks = 0; ks < 16; ++ks) {
            const bf16x8_t b = *(const bf16x8_t*)(xbase + ks * 512);
            acc = __builtin_amdgcn_mfma_f32_32x32x16_bf16(apre[ks], b, acc, 0, 0, 0);
        }
        #pragma unroll
        for (int r = 0; r < 16; ++r) {
            const int code = mt * 32 + half * 4 + ((r & 3) + 8 * (r >> 2));
            if (acc[r] > best) { best = acc[r]; bi = code; }
        }
    }

    // ---- combine the two k-half lanes (same hw row, disjoint code subsets)
    {
        const float ov = __shfl_xor(best, 32);
        const int   oi = __shfl_xor(bi, 32);
        if (ov > best || (ov == best && oi < bi)) { best = ov; bi = oi; }
    }

    // ---- xt is dead: overlay result arrays on it (saves 1.5 KB -> LDS = 32 KB
    // exactly -> 4 blocks/CU). Barrier first: all waves past their xt reads.
    __syncthreads();
    float* smin = (float*)xt;          // [2][64]
    int*   sidx = (int*)(xt + 128);    // [2][64]
    int*   sfin = (int*)(xt + 256);    // [64]
    if (lane < 32) {
        smin[ch * 64 + nt * 32 + lane] = best;
        sidx[ch * 64 + nt * 32 + lane] = bi;
    }
    __syncthreads();

    // ---- wave 0: combine code halves per row, publish indices, loss partial.
    // Other waves contribute their ||x||^2 partials directly.
    if (w == 0) {
        float b0 = smin[lane]; int i0 = sidx[lane];
        const float b1 = smin[64 + lane]; const int i1 = sidx[64 + lane];
        if (b1 > b0) { b0 = b1; i0 = i1; }
        sfin[lane] = i0;
        float ls = -2.f * b0;
        #pragma unroll
        for (int m = 32; m; m >>= 1) ls += __shfl_xor(ls, m);
        if (lane == 0) atomicAdd(loss_accum, ls + sqw);
    } else {
        if (lane == 0) atomicAdd(loss_accum, sqw);
    }
    __syncthreads();

    // ---- epilogue: gather fp32 codebook rows, dwordx4 stores along hw
    {
        const int q  = t & 15;     // rows 4q..4q+3
        const int dg = t >> 4;     // 0..15 -> d in [dg*16, dg*16+16)
        const int c0 = sfin[4 * q + 0], c1 = sfin[4 * q + 1];
        const int c2 = sfin[4 * q + 2], c3 = sfin[4 * q + 3];
        const float* r0 = cb + c0 * DIM;
        const float* r1 = cb + c1 * DIM;
        const float* r2 = cb + c2 * DIM;
        const float* r3 = cb + c3 * DIM;
        float* ob = out + (size_t)batch * (DIM * 1024) + hw0 + 4 * q;
        #pragma unroll 4
        for (int j = 0; j < 16; ++j) {
            const int d = dg * 16 + j;
            f32x4_t v; v.x = r0[d]; v.y = r1[d]; v.z = r2[d]; v.w = r3[d];
            *(f32x4_t*)(ob + (size_t)d * 1024) = v;
        }
    }
}

// ---- finalize loss ----
__global__ void vq_final(const float* __restrict__ loss_accum, float* __restrict__ out_loss) {
    *out_loss = 1.25f * (*loss_accum) / 16777216.f;
}

extern "C" void kernel_launch(void* const* d_in, const int* in_sizes, int n_in,
                              void* d_out, int out_size, void* d_ws, size_t ws_size,
                              hipStream_t stream) {
    const float* x  = (const float*)d_in[0];   // [64,256,32,32]
    const float* cb = (const float*)d_in[1];   // [1024,256]
    float* out = (float*)d_out;                // 16777216 + 1

    char* ws = (char*)d_ws;
    float* loss_accum = (float*)ws;                        // 4 B
    char*  cbsw       = ws + 1024;                         // 512 KB, A-frag order
    float* nh_ord     = (float*)(ws + 1024 + 512 * 1024);  // 4 KB

    hipMemsetAsync(loss_accum, 0, sizeof(float), stream);
    vq_prep<<<dim3(256), dim3(256), 0, stream>>>(cb, cbsw, nh_ord);
    vq_main<<<dim3(1024), dim3(256), 0, stream>>>(x, cb, (const bf16x8_t*)cbsw, nh_ord,
                                                  out, loss_accum);
    vq_final<<<dim3(1), dim3(1), 0, stream>>>(loss_accum, out + 16777216);
}